// Round 6
// baseline (624.150 us; speedup 1.0000x reference)
//
#include <hip/hip_runtime.h>
#include <hip/hip_bf16.h>

// ---------------------------------------------------------------------------
// Lfm2ShortConv decode step (B=2048, H=2048, K=4, P=8192, f32 in/out):
//   proj = hs @ w_in.T ; Bg,Cg,x = split(proj)
//   bx = Bg*x ; conv_out = [state | bx] . conv_w ; y = (Cg*conv_out) @ w_out.T
//   new_state = scatter(state, idx, [state[...,1:], bx])
// R2: touched-row state write fused into elemwise. (502.75us)
// R3: GEMM BK=64 + T2 XOR swizzle.
// R4/R6: untouched-row pool copy fused into GEMM1 as interleaved copy blocks
//        (verified: copy ~free; gemm1_fused 139us).
// R7: (a) elemwise fused into GEMM1 epilogue via 3-pass per-block structure:
//         block owns 128x128 (batch x h) tile, runs gemm_core 3x (Bg/Cg/x
//         planes of w_in), packs Bg/Cg/x accs to bf16 (same numerics as the
//         old proj_bf round-trip), computes conv+gate in-register, writes
//         state_out + g_bf directly. Deletes elemwise launch + 49MB proj
//         traffic. Same total K-iters (256blk x 96it = 768 x 32).
//     (b) gemm2_ws: 512thr, two 4-wave groups split K in-block, combine via
//         k-major LDS stash (conflict-free), write split-K2 partials;
//         halves partial traffic, reduce4 -> reduce2. 16 waves/CU kept.
// ---------------------------------------------------------------------------

typedef __bf16 bf16x8 __attribute__((ext_vector_type(8)));
typedef float f32x4 __attribute__((ext_vector_type(4)));

__device__ __forceinline__ unsigned short f2bf(float f) {
    union { float f; unsigned int u; } c; c.f = f;
    unsigned int u = c.u;
    u = u + 0x7FFFu + ((u >> 16) & 1u);   // RNE
    return (unsigned short)(u >> 16);
}
__device__ __forceinline__ float bf2f(unsigned short u) {
    union { unsigned int i; float f; } c; c.i = ((unsigned int)u) << 16;
    return c.f;
}

// ---- prep: all three f32->bf16 converts in one launch + inv-map init ------
__global__ void prep(const float4* __restrict__ hs, const float4* __restrict__ wi,
                     const float4* __restrict__ wo,
                     ushort4* __restrict__ hs_bf, ushort4* __restrict__ wi_bf,
                     ushort4* __restrict__ wo_bf,
                     int* __restrict__ inv, int P,
                     int n1, int n2, int n3) {
    int i = blockIdx.x * blockDim.x + threadIdx.x;
    if (i < P) inv[i] = -1;
    const float4* s; ushort4* d; int j = i;
    if (j < n1)            { s = hs; d = hs_bf; }
    else if ((j -= n1) < n2) { s = wi; d = wi_bf; }
    else if ((j -= n2) < n3) { s = wo; d = wo_bf; }
    else return;
    float4 v = s[j];
    ushort4 o; o.x = f2bf(v.x); o.y = f2bf(v.y); o.z = f2bf(v.z); o.w = f2bf(v.w);
    d[j] = o;
}

__global__ void scatter_inv(const int* __restrict__ idx, int* __restrict__ inv, int B) {
    int b = blockIdx.x * blockDim.x + threadIdx.x;
    if (b < B) inv[idx[b]] = b;
}

// -------------------- bf16 GEMM core (shared inline body) ------------------
// 128x128 tile, BK=64, 4 waves (tl in [0,256)), 4x4 16x16x32 MFMA tiles per
// wave, 2 K-halves.  LDS tiles [128][64] bf16 with XOR swizzle:
//   LDS[row][c ^ ((row&7)*8)] holds global[row][c]  (c, swizzle in elems)

#define GTILE 128
#define GBK 64

__device__ __forceinline__ void gl_lds16(const unsigned short* g, unsigned short* l) {
    __builtin_amdgcn_global_load_lds(
        (const __attribute__((address_space(1))) unsigned int*)g,
        (__attribute__((address_space(3))) unsigned int*)l,
        16, 0, 0);
}

// computes acc[4][4] for tile (bm,bn), K range [kb, kb+ksplit)
__device__ __forceinline__ void gemm_core(
    const unsigned short* __restrict__ A, const unsigned short* __restrict__ B,
    int K, int bm, int bn, int kb, int ksplit,
    unsigned short* Asm, unsigned short* Bsm, f32x4 (&acc)[4][4], int tl)
{
    const int lane = tl & 63;
    const int wave = tl >> 6;
    const int quad = lane >> 4;
    const int l16  = lane & 15;

    const int wm = (wave >> 1) * 64;
    const int wn = (wave & 1) * 64;

    // staging: round k4 covers rows k4*32 + (tl>>3); lane's 16B lands at
    // linear LDS byte k4*4096 + tl*16 -> row = k4*32 + tl>>3,
    // colbyte = (tl&7)*16.  Source col pre-swizzled by (row&7)*8 elems.
    const int sr = tl >> 3;                               // 0..31
    const int scsw = (((tl & 7) ^ (sr & 7)) * 8);         // swizzled col (elems)
    const unsigned short* Ag[4];
    const unsigned short* Bg[4];
#pragma unroll
    for (int k4 = 0; k4 < 4; k4++) {
        Ag[k4] = A + (size_t)(bm + k4 * 32 + sr) * K + scsw;
        Bg[k4] = B + (size_t)(bn + k4 * 32 + sr) * K + scsw;
    }

    for (int kt = kb; kt < kb + ksplit; kt += GBK) {
        __syncthreads();
#pragma unroll
        for (int k4 = 0; k4 < 4; k4++) {
            gl_lds16(Ag[k4] + kt, Asm + k4 * 2048 + wave * 512);
            gl_lds16(Bg[k4] + kt, Bsm + k4 * 2048 + wave * 512);
        }
        __syncthreads();

#pragma unroll
        for (int kk = 0; kk < 2; kk++) {
            bf16x8 a[4], b[4];
            // row = wm + i*16 + l16 -> row&7 == l16&7 (wm, i*16 are 16-aligned)
            const int csw = (kk * 32 + quad * 8) ^ ((l16 & 7) * 8);
#pragma unroll
            for (int i = 0; i < 4; i++)
                a[i] = *(const bf16x8*)&Asm[(wm + i * 16 + l16) * GBK + csw];
#pragma unroll
            for (int j = 0; j < 4; j++)
                b[j] = *(const bf16x8*)&Bsm[(wn + j * 16 + l16) * GBK + csw];
#pragma unroll
            for (int i = 0; i < 4; i++)
#pragma unroll
                for (int j = 0; j < 4; j++)
                    acc[i][j] = __builtin_amdgcn_mfma_f32_16x16x32_bf16(
                        a[i], b[j], acc[i][j], 0, 0, 0);
        }
    }
}

// pack f32x4 acc tile -> 2 u32 of bf16 pairs per (i,j)
__device__ __forceinline__ void pack_acc(const f32x4 (&acc)[4][4], unsigned int (&dst)[32]) {
#pragma unroll
    for (int i = 0; i < 4; i++)
#pragma unroll
        for (int j = 0; j < 4; j++) {
            dst[(i * 4 + j) * 2 + 0] =
                (unsigned int)f2bf(acc[i][j][0]) | ((unsigned int)f2bf(acc[i][j][1]) << 16);
            dst[(i * 4 + j) * 2 + 1] =
                (unsigned int)f2bf(acc[i][j][2]) | ((unsigned int)f2bf(acc[i][j][3]) << 16);
        }
}

// -------- GEMM1 + elemwise fused (+ interleaved untouched-row pool copy) ---
// Grid 384 = 256 compute (id%3 in {0,1}) + 128 copy (id%3==2) blocks.
// Compute block gid in [0,256): bm = (gid>>4)*128, bh = (gid&15)*128.
// Three gemm_core passes over the Bg/Cg/x planes of w_in, packed to bf16;
// epilogue = old elemwise in-register (state_out + g_bf writes).
__global__ __launch_bounds__(256) void gemm1_fused3(
    const unsigned short* __restrict__ A,    // hs_bf [B,K]
    const unsigned short* __restrict__ Wb,   // w_in_bf [3H,K]
    int H, int K,
    const int* __restrict__ idx,             // [B]
    const float* __restrict__ conv_w,        // [H,4]
    const float* __restrict__ cs_in,         // [P,H,3]
    const int* __restrict__ inv,             // [P]
    float* __restrict__ state_out,           // [P,H,3]
    unsigned short* __restrict__ g_out,      // [B,H] bf16
    int P, int NC)
{
    __shared__ __align__(16) unsigned short Asm[GTILE * GBK];
    __shared__ __align__(16) unsigned short Bsm[GTILE * GBK];

    const int id = blockIdx.x;
    const int q = id / 3, r = id % 3;
    const int HL = 3 * H;
    if (r == 2) {
        // ---- copy role: stream untouched pool rows (R4/R6-verified form) --
        int n4 = HL / 4;
        for (int p = q; p < P; p += NC) {
            if (inv[p] >= 0) continue;
            const float4* s4 = (const float4*)(cs_in + (size_t)p * HL);
            float4* d4 = (float4*)(state_out + (size_t)p * HL);
#pragma unroll 6
            for (int f = threadIdx.x; f < n4; f += 256) d4[f] = s4[f];
        }
        return;
    }
    const int gid = q * 2 + r;                 // [0,256)
    const int bm = (gid >> 4) * GTILE;         // batch tile
    const int bh = (gid & 15) * GTILE;         // h tile

    const int tid = threadIdx.x;

    unsigned int pb[32], pc[32], px[32];
    {
        f32x4 acc[4][4] = {};
        gemm_core(A, Wb, K, bm, bh, 0, K, Asm, Bsm, acc, tid);
        pack_acc(acc, pb);
    }
    {
        f32x4 acc[4][4] = {};
        gemm_core(A, Wb + (size_t)H * K, K, bm, bh, 0, K, Asm, Bsm, acc, tid);
        pack_acc(acc, pc);
    }
    {
        f32x4 acc[4][4] = {};
        gemm_core(A, Wb + (size_t)2 * H * K, K, bm, bh, 0, K, Asm, Bsm, acc, tid);
        pack_acc(acc, px);
    }

    // ---- fused elemwise epilogue (identical math to the old kernel) ----
    const int lane = tid & 63;
    const int wave = tid >> 6;
    const int quad = lane >> 4;
    const int l16  = lane & 15;
    const int wm = (wave >> 1) * 64;
    const int wn = (wave & 1) * 64;
#pragma unroll
    for (int i = 0; i < 4; i++) {
#pragma unroll
        for (int j = 0; j < 4; j++) {
            const int hcol = bh + wn + j * 16 + l16;
            const float4 cw = *(const float4*)(conv_w + 4 * hcol);
            const int k2 = (i * 4 + j) * 2;
#pragma unroll
            for (int rr = 0; rr < 4; rr++) {
                const int brow = bm + wm + i * 16 + quad * 4 + rr;
                const unsigned int ub = pb[k2 + (rr >> 1)];
                const unsigned int uc = pc[k2 + (rr >> 1)];
                const unsigned int ux = px[k2 + (rr >> 1)];
                const int sh = (rr & 1) * 16;
                const float Bg = bf2f((unsigned short)(ub >> sh));
                const float Cg = bf2f((unsigned short)(uc >> sh));
                const float xv = bf2f((unsigned short)(ux >> sh));
                const float bx = Bg * xv;
                const int slot = idx[brow];
                const float* cs = cs_in + ((size_t)slot * H + hcol) * 3;
                const float c0 = cs[0], c1 = cs[1], c2 = cs[2];
                const float co = c0 * cw.x + c1 * cw.y + c2 * cw.z + bx * cw.w;
                float* so = state_out + ((size_t)slot * H + hcol) * 3;
                so[0] = c1; so[1] = c2; so[2] = bx;
                g_out[(size_t)brow * H + hcol] = f2bf(Cg * co);
            }
        }
    }
}

// -------- GEMM2: 512thr, in-block wave-split-K (2 groups), split-K2 -------
// Group grp (tid>>8) covers K range [blockIdx.z*K/2 + grp*K/4, +K/4).
// Group 1 stashes acc k-major in LDS (conflict-free), group 0 adds and
// writes the split-K2 f32 partial.
__global__ __launch_bounds__(512) void gemm2_ws(
    const unsigned short* __restrict__ A,  // g_bf [M,K]
    const unsigned short* __restrict__ B,  // w_out_bf [N,K]
    float* __restrict__ part,              // [2][M,N] f32
    int M, int N, int K)
{
    __shared__ __align__(16) unsigned short smem[4 * GTILE * GBK]; // 64 KiB

    const int tid = threadIdx.x;
    const int grp = tid >> 8;
    const int tl  = tid & 255;

    const int bn = blockIdx.x * GTILE;
    const int bm = blockIdx.y * GTILE;
    const int kq = K >> 2;                                  // 512
    const int kb = blockIdx.z * (K >> 1) + grp * kq;

    unsigned short* As = smem + grp * 2 * GTILE * GBK;
    unsigned short* Bs = As + GTILE * GBK;

    f32x4 acc[4][4] = {};
    gemm_core(A, B, K, bm, bn, kb, kq, As, Bs, acc, tl);

    __syncthreads();                       // staging reads done in both groups
    float* stash = (float*)smem;           // 16384 f32 = 64 KiB
    if (grp == 1) {
#pragma unroll
        for (int i = 0; i < 4; i++)
#pragma unroll
            for (int j = 0; j < 4; j++)
#pragma unroll
                for (int rr = 0; rr < 4; rr++)
                    stash[((i * 4 + j) * 4 + rr) * 256 + tl] = acc[i][j][rr];
    }
    __syncthreads();
    if (grp == 0) {
        float* Cp = part + (size_t)blockIdx.z * M * N;
        const int lane = tl & 63;
        const int wave = tl >> 6;
        const int quad = lane >> 4;
        const int l16  = lane & 15;
        const int wm = (wave >> 1) * 64;
        const int wn = (wave & 1) * 64;
#pragma unroll
        for (int i = 0; i < 4; i++)
#pragma unroll
            for (int j = 0; j < 4; j++)
#pragma unroll
                for (int rr = 0; rr < 4; rr++) {
                    int row = bm + wm + i * 16 + quad * 4 + rr;
                    int col = bn + wn + j * 16 + l16;
                    Cp[(size_t)row * N + col] =
                        acc[i][j][rr] + stash[((i * 4 + j) * 4 + rr) * 256 + tl];
                }
    }
}

// -------- reduce: y = partial0 + partial1 ----------------------------------
__global__ void reduce2(const float4* __restrict__ p0, const float4* __restrict__ p1,
                        float4* __restrict__ y, int n4) {
    int i = blockIdx.x * blockDim.x + threadIdx.x;
    if (i >= n4) return;
    float4 a = p0[i], b = p1[i];
    float4 o; o.x = a.x + b.x; o.y = a.y + b.y; o.z = a.z + b.z; o.w = a.w + b.w;
    y[i] = o;
}

// ---------------------------------------------------------------------------
extern "C" void kernel_launch(void* const* d_in, const int* in_sizes, int n_in,
                              void* d_out, int out_size, void* d_ws, size_t ws_size,
                              hipStream_t stream) {
    const float* hs         = (const float*)d_in[0];
    const float* conv_state = (const float*)d_in[1];
    const int*   idx        = (const int*)d_in[2];
    const float* w_in       = (const float*)d_in[3];
    const float* w_out      = (const float*)d_in[4];
    const float* conv_w     = (const float*)d_in[5];

    const int B  = in_sizes[2];                       // 2048
    const int H  = in_sizes[0] / B;                   // 2048
    const int Kc = in_sizes[5] / H;                   // 4
    const int Lc = Kc - 1;                            // 3
    const int P  = (int)((long long)in_sizes[1] / ((long long)H * Lc)); // 8192

    float* y_out     = (float*)d_out;                 // [B,H]
    float* state_out = y_out + (size_t)B * H;         // [P,H,3]

    // workspace layout (proj_bf removed in R7)
    unsigned short* hs_bf    = (unsigned short*)d_ws;                    // B*H
    unsigned short* w_in_bf  = hs_bf + (size_t)B * H;                    // 3H*H
    unsigned short* w_out_bf = w_in_bf + (size_t)3 * H * H;              // H*H
    unsigned short* g_bf     = w_out_bf + (size_t)H * H;                 // B*H
    float*          part     = (float*)(g_bf + (size_t)B * H);           // 2*B*H
    int*            inv      = (int*)(part + (size_t)2 * B * H);         // P

    const int thr = 256;

    // 1) converts + inv init (one launch)
    {
        int n1 = B * H / 4, n2 = 3 * H * H / 4, n3 = H * H / 4;
        int tot = n1 + n2 + n3;
        prep<<<(tot + thr - 1) / thr, thr, 0, stream>>>(
            (const float4*)hs, (const float4*)w_in, (const float4*)w_out,
            (ushort4*)hs_bf, (ushort4*)w_in_bf, (ushort4*)w_out_bf,
            inv, P, n1, n2, n3);
    }
    scatter_inv<<<(B + thr - 1) / thr, thr, 0, stream>>>(idx, inv, B);

    // 2) GEMM1 + elemwise fused (+ pool copy): writes g_bf, state_out
    {
        int ncomp = (B / GTILE) * (H / GTILE);        // 256
        int NC    = ncomp / 2;                        // 128 copy blocks
        gemm1_fused3<<<ncomp + NC, 256, 0, stream>>>(
            hs_bf, w_in_bf, H, H, idx, conv_w, conv_state, inv,
            state_out, g_bf, P, NC);
    }

    // 3) GEMM2 wave-split + split-K2 partials, then reduce2 into y
    {
        dim3 grid(H / GTILE, B / GTILE, 2);
        gemm2_ws<<<grid, 512, 0, stream>>>(g_bf, w_out_bf, part, B, H, H);
        int n4 = B * H / 4;
        reduce2<<<(n4 + thr - 1) / thr, thr, 0, stream>>>(
            (const float4*)part, (const float4*)(part + (size_t)B * H),
            (float4*)y_out, n4);
    }
}